// Round 2
// baseline (247.756 us; speedup 1.0000x reference)
//
#include <hip/hip_runtime.h>
#include <hip/hip_bf16.h>

#define NN 100000
#define CC 128
#define KK 32
#define BB 64

// ---------------------------------------------------------------------------
// Kernel Z: zero the pooled-output region of d_out (harness poisons 0xAA).
// ---------------------------------------------------------------------------
__global__ __launch_bounds__(256) void hp_zero_out(float* __restrict__ out) {
    int idx = (blockIdx.x * 256 + threadIdx.x) * 4;
    if (idx < BB * KK * CC) {
        float4 z = make_float4(0.f, 0.f, 0.f, 0.f);
        *(float4*)(out + idx) = z;
    }
}

// ---------------------------------------------------------------------------
// Fused kernel: block = 64 nodes, 256 threads (4 waves), lane = node.
//  phase 1: h = relu(x@W1+b1). Wave w computes channels [32w,32w+32) for all
//           64 nodes. W1 from SGPR scalar loads (uniform), x from LDS
//           (1 swizzled ds_read_b128 per 4 j). 32 FMA/lane/j -> VALU-bound.
//  phase 2: partial logits over wave's 32 channels (W2 via SGPR).
//  phase 2b: tree-reduce partials across waves through LDS (2 rounds).
//  phase 3: wave 0 does softmax in-registers per node, writes s to global
//           (coalesced per-lane rows) and to LDS for phase 4.
//  phase 4: out[b] += s^T x for block's nodes; flush 16 atomics/thread per
//           (uniform) graph-id change (~1.04 flushes/block).
// LDS: xs 33.0KB + pl 18.0KB = 51.0KB -> 3 blocks/CU (12 waves/CU).
// ---------------------------------------------------------------------------
__global__ __launch_bounds__(256, 3) void hp_fused(
    const float* __restrict__ x,
    const int* __restrict__ batch,
    const float* __restrict__ W1,
    const float* __restrict__ b1,
    const float* __restrict__ W2,
    const float* __restrict__ b2,
    float* __restrict__ s_out,
    float* __restrict__ out)
{
    __shared__ float4 xs4[64][33];               // x rows; f4-col swizzled; +1 f4 pad
    __shared__ alignas(16) float pl[2][64][36];  // partial logits; later ss[64][36]

    const int t    = threadIdx.x;
    const int wave = __builtin_amdgcn_readfirstlane(t >> 6);
    const int lane = t & 63;
    const int base = blockIdx.x * 64;
    const int nvalid = min(64, NN - base);

    // ---- stage x: 32KB contiguous, fully coalesced float4 loads ----
    #pragma unroll
    for (int i = 0; i < 8; ++i) {
        int f  = t + 256 * i;          // flat f4 index within block tile
        int n  = f >> 5;               // 32 f4 per 128-float row
        int cf = f & 31;
        int ng = base + n;
        if (ng >= NN) ng = NN - 1;     // clamp (garbage rows gated by ss=0)
        float4 v = ((const float4*)x)[(size_t)ng * 32 + cf];
        xs4[n][cf ^ ((n >> 3) & 3)] = v;
    }
    __syncthreads();

    // ---- phase 1: H for this wave's 32 channels ----
    const int cbase = __builtin_amdgcn_readfirstlane((t >> 6) << 5);
    const int swz   = (lane >> 3) & 3;

    float acc[32];
    #pragma unroll
    for (int c = 0; c < 32; ++c) acc[c] = 0.f;

    for (int j4 = 0; j4 < CC; j4 += 4) {
        float4 xv = xs4[lane][(j4 >> 2) ^ swz];
        const float* Wr = W1 + (size_t)j4 * CC + cbase;   // uniform -> s_load
        #pragma unroll
        for (int jj = 0; jj < 4; ++jj) {
            const float xj = (jj == 0) ? xv.x : (jj == 1) ? xv.y : (jj == 2) ? xv.z : xv.w;
            #pragma unroll
            for (int c = 0; c < 32; ++c)
                acc[c] = fmaf(Wr[jj * CC + c], xj, acc[c]);
        }
    }
    {
        const float* b1p = b1 + cbase;                    // uniform -> s_load
        #pragma unroll
        for (int c = 0; c < 32; ++c)
            acc[c] = fmaxf(acc[c] + b1p[c], 0.f);
    }

    // ---- phase 2: partial logits over this wave's channels ----
    float lg[32];
    #pragma unroll
    for (int k = 0; k < 32; ++k) lg[k] = 0.f;
    #pragma unroll 4
    for (int c = 0; c < 32; ++c) {
        const float* W2r = W2 + (size_t)(cbase + c) * KK; // uniform -> s_load
        const float hc = acc[c];
        #pragma unroll
        for (int k = 0; k < 32; ++k)
            lg[k] = fmaf(W2r[k], hc, lg[k]);
    }

    // ---- phase 2b: cross-wave reduction (2 rounds through LDS) ----
    if (wave >= 2) {
        float* p = &pl[wave - 2][lane][0];
        #pragma unroll
        for (int k = 0; k < 32; k += 4)
            *(float4*)(p + k) = make_float4(lg[k], lg[k+1], lg[k+2], lg[k+3]);
    }
    __syncthreads();
    if (wave < 2) {
        const float* p = &pl[wave][lane][0];
        #pragma unroll
        for (int k = 0; k < 32; k += 4) {
            float4 v = *(const float4*)(p + k);
            lg[k] += v.x; lg[k+1] += v.y; lg[k+2] += v.z; lg[k+3] += v.w;
        }
    }
    __syncthreads();
    if (wave == 1) {
        float* p = &pl[0][lane][0];
        #pragma unroll
        for (int k = 0; k < 32; k += 4)
            *(float4*)(p + k) = make_float4(lg[k], lg[k+1], lg[k+2], lg[k+3]);
    }
    __syncthreads();

    // ---- phase 3: wave 0 finishes logits, softmax, writes s ----
    if (wave == 0) {
        const float* p = &pl[0][lane][0];
        #pragma unroll
        for (int k = 0; k < 32; k += 4) {
            float4 v = *(const float4*)(p + k);
            lg[k] += v.x; lg[k+1] += v.y; lg[k+2] += v.z; lg[k+3] += v.w;
        }
        float m = -3.4e38f;
        #pragma unroll
        for (int k = 0; k < 32; ++k) {
            lg[k] += b2[k];                               // uniform -> s_load
            m = fmaxf(m, lg[k]);
        }
        float sum = 0.f;
        #pragma unroll
        for (int k = 0; k < 32; ++k) {
            lg[k] = __expf(lg[k] - m);
            sum += lg[k];
        }
        const float inv = 1.f / sum;
        const bool valid = lane < nvalid;
        float* sp = &pl[0][0][0] + lane * 36;             // ss[lane][k]
        float* gp = s_out + (size_t)(base + lane) * KK;
        #pragma unroll
        for (int k = 0; k < 32; k += 4) {
            float4 sv = valid
                ? make_float4(lg[k] * inv, lg[k+1] * inv, lg[k+2] * inv, lg[k+3] * inv)
                : make_float4(0.f, 0.f, 0.f, 0.f);
            *(float4*)(sp + k) = sv;
            if (valid) *(float4*)(gp + k) = sv;
        }
    }
    __syncthreads();

    // ---- phase 4: out[b,k,c] += s[n,k] * x[n,c], atomic flush on id change --
    const int c0  = (t & 31) * 4;
    const int cf0 = t & 31;
    const int k0  = (t >> 5) * 4;
    const float* ssb = &pl[0][0][0];

    float a4[4][4] = {{0.f}};
    int cur = -1;

    for (int n = 0; n < 64; ++n) {
        int bidx = base + n; if (bidx >= NN) bidx = NN - 1;
        const int bid = __builtin_amdgcn_readfirstlane(batch[bidx]);
        if (bid != cur) {
            if (cur >= 0) {
                float* op = out + (size_t)cur * KK * CC;
                #pragma unroll
                for (int a = 0; a < 4; ++a)
                    #pragma unroll
                    for (int q = 0; q < 4; ++q) {
                        atomicAdd(op + (k0 + a) * CC + c0 + q, a4[a][q]);
                        a4[a][q] = 0.f;
                    }
            }
            cur = bid;
        }
        const float4 xv = xs4[n][cf0 ^ ((n >> 3) & 3)];
        const float4 sv = *(const float4*)(ssb + n * 36 + k0);
        a4[0][0] = fmaf(sv.x, xv.x, a4[0][0]); a4[0][1] = fmaf(sv.x, xv.y, a4[0][1]);
        a4[0][2] = fmaf(sv.x, xv.z, a4[0][2]); a4[0][3] = fmaf(sv.x, xv.w, a4[0][3]);
        a4[1][0] = fmaf(sv.y, xv.x, a4[1][0]); a4[1][1] = fmaf(sv.y, xv.y, a4[1][1]);
        a4[1][2] = fmaf(sv.y, xv.z, a4[1][2]); a4[1][3] = fmaf(sv.y, xv.w, a4[1][3]);
        a4[2][0] = fmaf(sv.z, xv.x, a4[2][0]); a4[2][1] = fmaf(sv.z, xv.y, a4[2][1]);
        a4[2][2] = fmaf(sv.z, xv.z, a4[2][2]); a4[2][3] = fmaf(sv.z, xv.w, a4[2][3]);
        a4[3][0] = fmaf(sv.w, xv.x, a4[3][0]); a4[3][1] = fmaf(sv.w, xv.y, a4[3][1]);
        a4[3][2] = fmaf(sv.w, xv.z, a4[3][2]); a4[3][3] = fmaf(sv.w, xv.w, a4[3][3]);
    }
    {
        float* op = out + (size_t)cur * KK * CC;
        #pragma unroll
        for (int a = 0; a < 4; ++a)
            #pragma unroll
            for (int q = 0; q < 4; ++q)
                atomicAdd(op + (k0 + a) * CC + c0 + q, a4[a][q]);
    }
}

// ---------------------------------------------------------------------------
extern "C" void kernel_launch(void* const* d_in, const int* in_sizes, int n_in,
                              void* d_out, int out_size, void* d_ws, size_t ws_size,
                              hipStream_t stream) {
    const float* x     = (const float*)d_in[0];
    const int*   batch = (const int*)d_in[1];
    const float* W1    = (const float*)d_in[2];
    const float* b1    = (const float*)d_in[3];
    const float* W2    = (const float*)d_in[4];
    const float* b2    = (const float*)d_in[5];

    float* out = (float*)d_out;                    // [B,K,C] = 262144 floats
    float* s   = out + (size_t)BB * KK * CC;       // [N,K]   = 3200000 floats

    hp_zero_out<<<(BB * KK * CC) / (256 * 4), 256, 0, stream>>>(out);
    const int nblocks = (NN + 63) / 64;            // 1563
    hp_fused<<<nblocks, 256, 0, stream>>>(x, batch, W1, b1, W2, b2, s, out);
}

// Round 3
// 205.352 us; speedup vs baseline: 1.2065x; 1.2065x over previous
//
#include <hip/hip_runtime.h>
#include <hip/hip_bf16.h>

#define NN 100000
#define CC 128
#define KK 32
#define BB 64
#define PANEL 16

// ---------------------------------------------------------------------------
// Kernel 1: per-graph node ranges. batch is sorted; bounds[b] = lower_bound(b),
// bounds[64] = NN.  One block, 128 threads (65 active).
// ---------------------------------------------------------------------------
__global__ __launch_bounds__(128) void hp_bounds(const int* __restrict__ batch,
                                                 int* __restrict__ bounds) {
    const int b = threadIdx.x;
    if (b <= BB) {
        int lo = 0, hi = NN;
        while (lo < hi) {
            const int mid = (lo + hi) >> 1;
            if (batch[mid] < b) lo = mid + 1; else hi = mid;
        }
        bounds[b] = lo;
    }
}

// ---------------------------------------------------------------------------
// Kernel 2: fused  h = relu(x@W1+b1);  s = softmax(h@W2+b2)  -> global s.
// Block = 64 nodes, 256 threads (4 waves), lane = node.
//   phase 1: wave w computes channels [32w,32w+32) for all 64 nodes; W1 via
//            SGPR scalar loads (wave-uniform), x via swizzled ds_read_b128.
//   phase 2: partial logits over wave's 32 channels (W2 via SGPR).
//   phase 2b: tree-reduce partials across waves through LDS (2 rounds).
//   phase 3: wave 0 softmax per node, coalesced float4 s store.
// LDS: xs 33.0KB + pl 18.0KB = 51.0KB -> 3 blocks/CU (12 waves/CU).
// ---------------------------------------------------------------------------
__global__ __launch_bounds__(256, 3) void hp_mlp(
    const float* __restrict__ x,
    const float* __restrict__ W1,
    const float* __restrict__ b1,
    const float* __restrict__ W2,
    const float* __restrict__ b2,
    float* __restrict__ s_out)
{
    __shared__ float4 xs4[64][33];               // x rows; f4-col swizzled; +1 f4 pad
    __shared__ alignas(16) float pl[2][64][36];  // partial logits

    const int t    = threadIdx.x;
    const int wave = __builtin_amdgcn_readfirstlane(t >> 6);
    const int lane = t & 63;
    const int base = blockIdx.x * 64;
    const int nvalid = min(64, NN - base);

    // ---- stage x: 32KB contiguous, fully coalesced float4 loads ----
    #pragma unroll
    for (int i = 0; i < 8; ++i) {
        int f  = t + 256 * i;          // flat f4 index within block tile
        int n  = f >> 5;               // 32 f4 per 128-float row
        int cf = f & 31;
        int ng = base + n;
        if (ng >= NN) ng = NN - 1;     // clamp (garbage rows never stored)
        float4 v = ((const float4*)x)[(size_t)ng * 32 + cf];
        xs4[n][cf ^ ((n >> 3) & 3)] = v;
    }
    __syncthreads();

    // ---- phase 1: H for this wave's 32 channels ----
    const int cbase = __builtin_amdgcn_readfirstlane((t >> 6) << 5);
    const int swz   = (lane >> 3) & 3;

    float acc[32];
    #pragma unroll
    for (int c = 0; c < 32; ++c) acc[c] = 0.f;

    for (int j4 = 0; j4 < CC; j4 += 4) {
        float4 xv = xs4[lane][(j4 >> 2) ^ swz];
        const float* Wr = W1 + (size_t)j4 * CC + cbase;   // uniform -> s_load
        #pragma unroll
        for (int jj = 0; jj < 4; ++jj) {
            const float xj = (jj == 0) ? xv.x : (jj == 1) ? xv.y : (jj == 2) ? xv.z : xv.w;
            #pragma unroll
            for (int c = 0; c < 32; ++c)
                acc[c] = fmaf(Wr[jj * CC + c], xj, acc[c]);
        }
    }
    {
        const float* b1p = b1 + cbase;                    // uniform -> s_load
        #pragma unroll
        for (int c = 0; c < 32; ++c)
            acc[c] = fmaxf(acc[c] + b1p[c], 0.f);
    }

    // ---- phase 2: partial logits over this wave's channels ----
    float lg[32];
    #pragma unroll
    for (int k = 0; k < 32; ++k) lg[k] = 0.f;
    #pragma unroll 4
    for (int c = 0; c < 32; ++c) {
        const float* W2r = W2 + (size_t)(cbase + c) * KK; // uniform -> s_load
        const float hc = acc[c];
        #pragma unroll
        for (int k = 0; k < 32; ++k)
            lg[k] = fmaf(W2r[k], hc, lg[k]);
    }

    // ---- phase 2b: cross-wave reduction (2 rounds through LDS) ----
    if (wave >= 2) {
        float* p = &pl[wave - 2][lane][0];
        #pragma unroll
        for (int k = 0; k < 32; k += 4)
            *(float4*)(p + k) = make_float4(lg[k], lg[k+1], lg[k+2], lg[k+3]);
    }
    __syncthreads();
    if (wave < 2) {
        const float* p = &pl[wave][lane][0];
        #pragma unroll
        for (int k = 0; k < 32; k += 4) {
            float4 v = *(const float4*)(p + k);
            lg[k] += v.x; lg[k+1] += v.y; lg[k+2] += v.z; lg[k+3] += v.w;
        }
    }
    __syncthreads();
    if (wave == 1) {
        float* p = &pl[0][lane][0];
        #pragma unroll
        for (int k = 0; k < 32; k += 4)
            *(float4*)(p + k) = make_float4(lg[k], lg[k+1], lg[k+2], lg[k+3]);
    }
    __syncthreads();

    // ---- phase 3: wave 0 finishes logits, softmax, stores s ----
    if (wave == 0) {
        const float* p = &pl[0][lane][0];
        #pragma unroll
        for (int k = 0; k < 32; k += 4) {
            float4 v = *(const float4*)(p + k);
            lg[k] += v.x; lg[k+1] += v.y; lg[k+2] += v.z; lg[k+3] += v.w;
        }
        float m = -3.4e38f;
        #pragma unroll
        for (int k = 0; k < 32; ++k) {
            lg[k] += b2[k];                               // uniform -> s_load
            m = fmaxf(m, lg[k]);
        }
        float sum = 0.f;
        #pragma unroll
        for (int k = 0; k < 32; ++k) {
            lg[k] = __expf(lg[k] - m);
            sum += lg[k];
        }
        const float inv = 1.f / sum;
        if (lane < nvalid) {
            float* gp = s_out + (size_t)(base + lane) * KK;
            #pragma unroll
            for (int k = 0; k < 32; k += 4)
                *(float4*)(gp + k) = make_float4(lg[k] * inv, lg[k+1] * inv,
                                                 lg[k+2] * inv, lg[k+3] * inv);
        }
    }
}

// ---------------------------------------------------------------------------
// Kernel 3: partial pooling. Block = (graph b, node-quarter p); 256 threads.
// part[blk] (32x128) = S_slice^T @ X_slice via 16-node LDS panels; thread owns
// a 4k x 4c register tile. Plain stores, zero atomics.
// ---------------------------------------------------------------------------
__global__ __launch_bounds__(256) void hp_pool(
    const float* __restrict__ x,
    const float* __restrict__ s,
    const int* __restrict__ bounds,
    float* __restrict__ part)
{
    __shared__ float xs[PANEL][132];      // +4 pad
    __shared__ float ss[PANEL][36];       // +4 pad

    const int b = blockIdx.x >> 2;
    const int p = blockIdx.x & 3;
    const int t = threadIdx.x;

    const int gs  = bounds[b];
    const int cnt = bounds[b + 1] - gs;
    const int n0  = gs + ((cnt * p) >> 2);
    const int n1  = gs + ((cnt * (p + 1)) >> 2);

    const int k0 = (t >> 5) * 4;
    const int c0 = (t & 31) * 4;

    float a4[4][4] = {{0.f}};

    for (int nb = n0; nb < n1; nb += PANEL) {
        const int m = min(PANEL, n1 - nb);
        __syncthreads();   // previous panel fully consumed
        #pragma unroll
        for (int i = 0; i < 2; ++i) {      // 512 f4 of x / 256 threads
            const int f = t + 256 * i;
            const int r = f >> 5, cf = f & 31;
            if (r < m)
                *(float4*)&xs[r][cf * 4] = ((const float4*)x)[(size_t)(nb + r) * 32 + cf];
        }
        if (t < 8 * PANEL) {               // 128 f4 of s
            const int r = t >> 3, kf = t & 7;
            if (r < m)
                *(float4*)&ss[r][kf * 4] = ((const float4*)s)[(size_t)(nb + r) * 8 + kf];
        }
        __syncthreads();

        for (int i = 0; i < m; ++i) {
            const float4 xv = *(const float4*)&xs[i][c0];
            const float4 sv = *(const float4*)&ss[i][k0];
            a4[0][0] = fmaf(sv.x, xv.x, a4[0][0]); a4[0][1] = fmaf(sv.x, xv.y, a4[0][1]);
            a4[0][2] = fmaf(sv.x, xv.z, a4[0][2]); a4[0][3] = fmaf(sv.x, xv.w, a4[0][3]);
            a4[1][0] = fmaf(sv.y, xv.x, a4[1][0]); a4[1][1] = fmaf(sv.y, xv.y, a4[1][1]);
            a4[1][2] = fmaf(sv.y, xv.z, a4[1][2]); a4[1][3] = fmaf(sv.y, xv.w, a4[1][3]);
            a4[2][0] = fmaf(sv.z, xv.x, a4[2][0]); a4[2][1] = fmaf(sv.z, xv.y, a4[2][1]);
            a4[2][2] = fmaf(sv.z, xv.z, a4[2][2]); a4[2][3] = fmaf(sv.z, xv.w, a4[2][3]);
            a4[3][0] = fmaf(sv.w, xv.x, a4[3][0]); a4[3][1] = fmaf(sv.w, xv.y, a4[3][1]);
            a4[3][2] = fmaf(sv.w, xv.z, a4[3][2]); a4[3][3] = fmaf(sv.w, xv.w, a4[3][3]);
        }
    }

    float* op = part + (size_t)blockIdx.x * KK * CC;
    #pragma unroll
    for (int a = 0; a < 4; ++a)
        *(float4*)&op[(k0 + a) * CC + c0] = make_float4(a4[a][0], a4[a][1], a4[a][2], a4[a][3]);
}

// ---------------------------------------------------------------------------
// Kernel 4: out[b] = sum of the 4 partial tiles.
// ---------------------------------------------------------------------------
__global__ __launch_bounds__(256) void hp_reduce(const float* __restrict__ part,
                                                 float* __restrict__ out) {
    const int i = (blockIdx.x * 256 + threadIdx.x) * 4;
    if (i < BB * KK * CC) {
        const int b = i >> 12;          // / 4096
        const int j = i & 4095;
        const float* pp = part + (size_t)b * 4 * 4096 + j;
        float4 v0 = *(const float4*)(pp + 0 * 4096);
        float4 v1 = *(const float4*)(pp + 1 * 4096);
        float4 v2 = *(const float4*)(pp + 2 * 4096);
        float4 v3 = *(const float4*)(pp + 3 * 4096);
        float4 r;
        r.x = (v0.x + v1.x) + (v2.x + v3.x);
        r.y = (v0.y + v1.y) + (v2.y + v3.y);
        r.z = (v0.z + v1.z) + (v2.z + v3.z);
        r.w = (v0.w + v1.w) + (v2.w + v3.w);
        *(float4*)(out + i) = r;
    }
}

// ---------------------------------------------------------------------------
extern "C" void kernel_launch(void* const* d_in, const int* in_sizes, int n_in,
                              void* d_out, int out_size, void* d_ws, size_t ws_size,
                              hipStream_t stream) {
    const float* x     = (const float*)d_in[0];
    const int*   batch = (const int*)d_in[1];
    const float* W1    = (const float*)d_in[2];
    const float* b1    = (const float*)d_in[3];
    const float* W2    = (const float*)d_in[4];
    const float* b2    = (const float*)d_in[5];

    float* out = (float*)d_out;                    // [B,K,C] = 262144 floats
    float* s   = out + (size_t)BB * KK * CC;       // [N,K]   = 3200000 floats

    int*   bounds = (int*)d_ws;                          // 65 ints
    float* part   = (float*)((char*)d_ws + 1024);        // [256][4096] = 4 MB

    hp_bounds<<<1, 128, 0, stream>>>(batch, bounds);
    hp_mlp<<<(NN + 63) / 64, 256, 0, stream>>>(x, W1, b1, W2, b2, s);
    hp_pool<<<BB * 4, 256, 0, stream>>>(x, s, bounds, part);
    hp_reduce<<<BB * KK * CC / (256 * 4), 256, 0, stream>>>(part, out);
}

// Round 4
// 199.813 us; speedup vs baseline: 1.2399x; 1.0277x over previous
//
#include <hip/hip_runtime.h>
#include <hip/hip_bf16.h>

#define NN 100000
#define CC 128
#define KK 32
#define BB 64

// ---------------------------------------------------------------------------
// Kernel 1: per-graph node ranges. batch is sorted; bounds[b] = lower_bound(b),
// bounds[64] = NN.  One block, 128 threads (65 active).
// ---------------------------------------------------------------------------
__global__ __launch_bounds__(128) void hp_bounds(const int* __restrict__ batch,
                                                 int* __restrict__ bounds) {
    const int b = threadIdx.x;
    if (b <= BB) {
        int lo = 0, hi = NN;
        while (lo < hi) {
            const int mid = (lo + hi) >> 1;
            if (batch[mid] < b) lo = mid + 1; else hi = mid;
        }
        bounds[b] = lo;
    }
}

// ---------------------------------------------------------------------------
// Kernel 2: fused  h = relu(x@W1+b1);  s = softmax(h@W2+b2)  -> global s.
// Block = 64 nodes, 256 threads (4 waves), lane = node.
//   phase 1: wave w computes channels [32w,32w+32) for all 64 nodes.
//            j-loop split into 8 quarters: 4 batched ds_read_b128 of x into
//            registers, then a PURE s_load(W1)+FMA stretch of 512 FMA — no
//            DS outstanding, so lgkmcnt waits only cover SMEM and the
//            compiler can chunk-prefetch W1 behind the FMA stream.
//   phase 2: partial logits over wave's 32 channels (W2 16KB, K$-resident).
//   phase 2b: tree-reduce partials across waves through LDS (2 rounds).
//   phase 3: wave 0 softmax per node, coalesced float4 s store.
// LDS: xs 33.0KB + pl 18.0KB = 51.0KB -> 3 blocks/CU (12 waves/CU).
// ---------------------------------------------------------------------------
__global__ __launch_bounds__(256, 3) void hp_mlp(
    const float* __restrict__ x,
    const float* __restrict__ W1,
    const float* __restrict__ b1,
    const float* __restrict__ W2,
    const float* __restrict__ b2,
    float* __restrict__ s_out)
{
    __shared__ float4 xs4[64][33];               // x rows; f4-col swizzled; +1 f4 pad
    __shared__ alignas(16) float pl[2][64][36];  // partial logits

    const int t    = threadIdx.x;
    const int wave = __builtin_amdgcn_readfirstlane(t >> 6);
    const int lane = t & 63;
    const int base = blockIdx.x * 64;
    const int nvalid = min(64, NN - base);

    // ---- stage x: 32KB contiguous, fully coalesced float4 loads ----
    #pragma unroll
    for (int i = 0; i < 8; ++i) {
        int f  = t + 256 * i;          // flat f4 index within block tile
        int n  = f >> 5;               // 32 f4 per 128-float row
        int cf = f & 31;
        int ng = base + n;
        if (ng >= NN) ng = NN - 1;     // clamp (garbage rows never stored)
        float4 v = ((const float4*)x)[(size_t)ng * 32 + cf];
        xs4[n][cf ^ ((n >> 3) & 3)] = v;
    }
    __syncthreads();

    // ---- phase 1: H for this wave's 32 channels ----
    const int cbase = __builtin_amdgcn_readfirstlane((t >> 6) << 5);
    const int swz   = (lane >> 3) & 3;

    float acc[32];
    #pragma unroll
    for (int c = 0; c < 32; ++c) acc[c] = 0.f;

    for (int q = 0; q < 8; ++q) {                 // 16 j per quarter
        float4 xq[4];
        #pragma unroll
        for (int jt = 0; jt < 4; ++jt)            // 4 batched ds_read_b128
            xq[jt] = xs4[lane][(q * 4 + jt) ^ swz];
        #pragma unroll
        for (int jt = 0; jt < 4; ++jt) {
            const float* Wr = W1 + (size_t)(q * 16 + jt * 4) * CC + cbase; // uniform
            #pragma unroll
            for (int jj = 0; jj < 4; ++jj) {
                const float xj = (jj == 0) ? xq[jt].x : (jj == 1) ? xq[jt].y
                               : (jj == 2) ? xq[jt].z : xq[jt].w;
                #pragma unroll
                for (int c = 0; c < 32; ++c)
                    acc[c] = fmaf(Wr[jj * CC + c], xj, acc[c]);
            }
        }
    }
    {
        const float* b1p = b1 + cbase;                    // uniform -> s_load
        #pragma unroll
        for (int c = 0; c < 32; ++c)
            acc[c] = fmaxf(acc[c] + b1p[c], 0.f);
    }

    // ---- phase 2: partial logits over this wave's channels ----
    float lg[32];
    #pragma unroll
    for (int k = 0; k < 32; ++k) lg[k] = 0.f;
    #pragma unroll 4
    for (int c = 0; c < 32; ++c) {
        const float* W2r = W2 + (size_t)(cbase + c) * KK; // uniform -> s_load
        const float hc = acc[c];
        #pragma unroll
        for (int k = 0; k < 32; ++k)
            lg[k] = fmaf(W2r[k], hc, lg[k]);
    }

    // ---- phase 2b: cross-wave reduction (2 rounds through LDS) ----
    if (wave >= 2) {
        float* p = &pl[wave - 2][lane][0];
        #pragma unroll
        for (int k = 0; k < 32; k += 4)
            *(float4*)(p + k) = make_float4(lg[k], lg[k+1], lg[k+2], lg[k+3]);
    }
    __syncthreads();
    if (wave < 2) {
        const float* p = &pl[wave][lane][0];
        #pragma unroll
        for (int k = 0; k < 32; k += 4) {
            float4 v = *(const float4*)(p + k);
            lg[k] += v.x; lg[k+1] += v.y; lg[k+2] += v.z; lg[k+3] += v.w;
        }
    }
    __syncthreads();
    if (wave == 1) {
        float* p = &pl[0][lane][0];
        #pragma unroll
        for (int k = 0; k < 32; k += 4)
            *(float4*)(p + k) = make_float4(lg[k], lg[k+1], lg[k+2], lg[k+3]);
    }
    __syncthreads();

    // ---- phase 3: wave 0 finishes logits, softmax, stores s ----
    if (wave == 0) {
        const float* p = &pl[0][lane][0];
        #pragma unroll
        for (int k = 0; k < 32; k += 4) {
            float4 v = *(const float4*)(p + k);
            lg[k] += v.x; lg[k+1] += v.y; lg[k+2] += v.z; lg[k+3] += v.w;
        }
        float m = -3.4e38f;
        #pragma unroll
        for (int k = 0; k < 32; ++k) {
            lg[k] += b2[k];                               // uniform -> s_load
            m = fmaxf(m, lg[k]);
        }
        float sum = 0.f;
        #pragma unroll
        for (int k = 0; k < 32; ++k) {
            lg[k] = __expf(lg[k] - m);
            sum += lg[k];
        }
        const float inv = 1.f / sum;
        if (lane < nvalid) {
            float* gp = s_out + (size_t)(base + lane) * KK;
            #pragma unroll
            for (int k = 0; k < 32; k += 4)
                *(float4*)(gp + k) = make_float4(lg[k] * inv, lg[k+1] * inv,
                                                 lg[k+2] * inv, lg[k+3] * inv);
        }
    }
}

// ---------------------------------------------------------------------------
// Kernel 3: partial pooling, pure streaming — NO LDS, NO barriers.
// Block = (graph b, slice p of nslices); 256 threads; thread owns a 4k x 4c
// register tile. Per node: one coalesced x float4 (shared by 8 k-groups via
// L1) + one broadcast s float4, 16 FMA. Plain stores of the partial tile.
// ---------------------------------------------------------------------------
__global__ __launch_bounds__(256) void hp_pool(
    const float* __restrict__ x,
    const float* __restrict__ s,
    const int* __restrict__ bounds,
    float* __restrict__ part,
    int nslices)
{
    const int b = blockIdx.x / nslices;
    const int p = blockIdx.x - b * nslices;
    const int t = threadIdx.x;

    const int gs  = bounds[b];
    const int cnt = bounds[b + 1] - gs;
    const int n0  = gs + (int)(((long long)cnt * p) / nslices);
    const int n1  = gs + (int)(((long long)cnt * (p + 1)) / nslices);

    const int k0 = (t >> 5) * 4;
    const int c0 = (t & 31) * 4;

    float a4[4][4] = {{0.f}};

    #pragma unroll 2
    for (int n = n0; n < n1; ++n) {
        const float4 xv = *(const float4*)(x + (size_t)n * CC + c0);
        const float4 sv = *(const float4*)(s + (size_t)n * KK + k0);
        a4[0][0] = fmaf(sv.x, xv.x, a4[0][0]); a4[0][1] = fmaf(sv.x, xv.y, a4[0][1]);
        a4[0][2] = fmaf(sv.x, xv.z, a4[0][2]); a4[0][3] = fmaf(sv.x, xv.w, a4[0][3]);
        a4[1][0] = fmaf(sv.y, xv.x, a4[1][0]); a4[1][1] = fmaf(sv.y, xv.y, a4[1][1]);
        a4[1][2] = fmaf(sv.y, xv.z, a4[1][2]); a4[1][3] = fmaf(sv.y, xv.w, a4[1][3]);
        a4[2][0] = fmaf(sv.z, xv.x, a4[2][0]); a4[2][1] = fmaf(sv.z, xv.y, a4[2][1]);
        a4[2][2] = fmaf(sv.z, xv.z, a4[2][2]); a4[2][3] = fmaf(sv.z, xv.w, a4[2][3]);
        a4[3][0] = fmaf(sv.w, xv.x, a4[3][0]); a4[3][1] = fmaf(sv.w, xv.y, a4[3][1]);
        a4[3][2] = fmaf(sv.w, xv.z, a4[3][2]); a4[3][3] = fmaf(sv.w, xv.w, a4[3][3]);
    }

    float* op = part + (size_t)blockIdx.x * KK * CC;
    #pragma unroll
    for (int a = 0; a < 4; ++a)
        *(float4*)&op[(k0 + a) * CC + c0] = make_float4(a4[a][0], a4[a][1], a4[a][2], a4[a][3]);
}

// ---------------------------------------------------------------------------
// Kernel 4: out[b] = sum of the nslices partial tiles.
// ---------------------------------------------------------------------------
__global__ __launch_bounds__(256) void hp_reduce(const float* __restrict__ part,
                                                 float* __restrict__ out,
                                                 int nslices) {
    const int i = (blockIdx.x * 256 + threadIdx.x) * 4;
    if (i < BB * KK * CC) {
        const int b = i >> 12;          // / 4096
        const int j = i & 4095;
        const float* pp = part + (size_t)b * nslices * 4096 + j;
        float4 r = make_float4(0.f, 0.f, 0.f, 0.f);
        for (int q = 0; q < nslices; ++q) {
            float4 v = *(const float4*)(pp + (size_t)q * 4096);
            r.x += v.x; r.y += v.y; r.z += v.z; r.w += v.w;
        }
        *(float4*)(out + i) = r;
    }
}

// ---------------------------------------------------------------------------
extern "C" void kernel_launch(void* const* d_in, const int* in_sizes, int n_in,
                              void* d_out, int out_size, void* d_ws, size_t ws_size,
                              hipStream_t stream) {
    const float* x     = (const float*)d_in[0];
    const int*   batch = (const int*)d_in[1];
    const float* W1    = (const float*)d_in[2];
    const float* b1    = (const float*)d_in[3];
    const float* W2    = (const float*)d_in[4];
    const float* b2    = (const float*)d_in[5];

    float* out = (float*)d_out;                    // [B,K,C] = 262144 floats
    float* s   = out + (size_t)BB * KK * CC;       // [N,K]   = 3200000 floats

    int*   bounds = (int*)d_ws;                          // 65 ints
    float* part   = (float*)((char*)d_ws + 1024);

    // slices per graph: prefer 16 (16 MB partials), fall back if ws is small
    int nslices = 16;
    while (nslices > 4 && ws_size < 1024 + (size_t)BB * nslices * KK * CC * 4)
        nslices >>= 1;

    hp_bounds<<<1, 128, 0, stream>>>(batch, bounds);
    hp_mlp<<<(NN + 63) / 64, 256, 0, stream>>>(x, W1, b1, W2, b2, s);
    hp_pool<<<BB * nslices, 256, 0, stream>>>(x, s, bounds, part, nslices);
    hp_reduce<<<BB * KK * CC / (256 * 4), 256, 0, stream>>>(part, out, nslices);
}

// Round 5
// 164.640 us; speedup vs baseline: 1.5048x; 1.2136x over previous
//
#include <hip/hip_runtime.h>
#include <hip/hip_bf16.h>

#define NN 100000
#define CC 128
#define KK 32
#define BB 64

typedef __bf16 bf16x8 __attribute__((ext_vector_type(8)));
typedef float  f32x4  __attribute__((ext_vector_type(4)));

__device__ __forceinline__ unsigned short f2bf(float v) {       // RNE bf16
    union { float f; unsigned u; } a; a.f = v;
    unsigned r = a.u + 0x7FFF + ((a.u >> 16) & 1);
    return (unsigned short)(r >> 16);
}
__device__ __forceinline__ float bf2f(unsigned short h) {
    union { unsigned u; float f; } a; a.u = ((unsigned)h) << 16;
    return a.f;
}

// ---------------------------------------------------------------------------
// Kernel 1 (prep): per-graph bounds + W1 -> bf16 hi/lo fragments.
// w1f layout: [split 2][kt 4][nt 8][lane 64][j 8] bf16;
//   element (kt,nt,lane,j) = W1[kt*32 + (lane>>4)*8 + j][nt*16 + (lane&15)]
// so an MFMA B-frag is one coalesced 16 B/lane load.  8 blocks x 256 thr.
// ---------------------------------------------------------------------------
__global__ __launch_bounds__(256) void hp_prep(const int* __restrict__ batch,
                                               const float* __restrict__ W1,
                                               int* __restrict__ bounds,
                                               unsigned short* __restrict__ w1f) {
    const int t = blockIdx.x * 256 + threadIdx.x;
    if (blockIdx.x == 0 && threadIdx.x <= BB) {
        const int b = threadIdx.x;
        int lo = 0, hi = NN;
        while (lo < hi) {
            const int mid = (lo + hi) >> 1;
            if (batch[mid] < b) lo = mid + 1; else hi = mid;
        }
        bounds[b] = lo;
    }
    for (int idx = t; idx < 16384; idx += 2048) {
        const int j    = idx & 7;
        const int lane = (idx >> 3) & 63;
        const int nt   = (idx >> 9) & 7;
        const int kt   = idx >> 12;
        const int k = kt * 32 + (lane >> 4) * 8 + j;
        const int n = nt * 16 + (lane & 15);
        const float w = W1[k * CC + n];
        const unsigned short h = f2bf(w);
        w1f[idx]         = h;
        w1f[16384 + idx] = f2bf(w - bf2f(h));
    }
}

// ---------------------------------------------------------------------------
// Kernel 2: h = relu(x@W1+b1) via split-bf16 MFMA; s = softmax(h@W2+b2).
// Block = 64 nodes, 256 threads (4 waves).
//  stage:   x tile converted to bf16 hi/lo directly in A-frag layout in LDS
//           (xa[sp][q=mt*4+kt][lane][j]); canonical lane*16 reads.
//  phase 1: wave w owns n-tiles {2w,2w+1}; 96 mfma_f32_16x16x32_bf16
//           (xh*wh + xl*wh + xh*wl); W frags = coalesced global loads (L2).
//  epilog:  bias+relu from C-frags -> hs[64][130] f32 (overlays dead xa).
//  phase 2: wave w computes logits k in [8w,8w+8) for all 64 nodes
//           (lane = node; hs row b64 reads; W2 via SMEM, K$-resident).
//  phase 3: logit transpose through lgT; wave 0 softmax + f4 s store.
// LDS: max(xa 32K, hs 33.3K) + lgT 8.4K = 41.7 KB -> 3 blocks/CU.
// ---------------------------------------------------------------------------
__global__ __launch_bounds__(256, 3) void hp_mlp(
    const float* __restrict__ x,
    const unsigned short* __restrict__ w1f,
    const float* __restrict__ b1,
    const float* __restrict__ W2,
    const float* __restrict__ b2,
    float* __restrict__ s_out)
{
    __shared__ __align__(16) char uni[33280];     // xa (32768 B) / hs (33280 B)
    __shared__ float lgT[KK * 66];                // [k][node], pad 66

    unsigned short* xa = (unsigned short*)uni;    // [sp][16][64][8]
    float*          hs = (float*)uni;             // [node][130]

    const int t    = threadIdx.x;
    const int wave = __builtin_amdgcn_readfirstlane(t >> 6);
    const int lane = t & 63;
    const int base = blockIdx.x * 64;
    const int nvalid = min(64, NN - base);

    // ---- stage x -> bf16 hi/lo in A-frag layout ----
    #pragma unroll
    for (int p = 0; p < 4; ++p) {
        const int q  = wave + 4 * p;              // frag block = mt*4 + kt
        const int mt = q >> 2, kt = q & 3;
        int n = base + mt * 16 + (lane & 15);
        if (n >= NN) n = NN - 1;
        const int ck = kt * 32 + (lane >> 4) * 8;
        const float4 va = *(const float4*)(x + (size_t)n * CC + ck);
        const float4 vb = *(const float4*)(x + (size_t)n * CC + ck + 4);
        float v[8] = {va.x, va.y, va.z, va.w, vb.x, vb.y, vb.z, vb.w};
        unsigned short hi[8], lo[8];
        #pragma unroll
        for (int j = 0; j < 8; ++j) {
            hi[j] = f2bf(v[j]);
            lo[j] = f2bf(v[j] - bf2f(hi[j]));
        }
        unsigned short* d0 = xa + (q * 64 + lane) * 8;
        unsigned short* d1 = d0 + 8192;
        *(ushort4*)(d0)     = make_ushort4(hi[0], hi[1], hi[2], hi[3]);
        *(ushort4*)(d0 + 4) = make_ushort4(hi[4], hi[5], hi[6], hi[7]);
        *(ushort4*)(d1)     = make_ushort4(lo[0], lo[1], lo[2], lo[3]);
        *(ushort4*)(d1 + 4) = make_ushort4(lo[4], lo[5], lo[6], lo[7]);
    }
    __syncthreads();

    // ---- phase 1: MFMA, wave owns n-tiles 2w, 2w+1 ----
    f32x4 acc[4][2];
    #pragma unroll
    for (int mt = 0; mt < 4; ++mt)
        #pragma unroll
        for (int nl = 0; nl < 2; ++nl)
            acc[mt][nl] = (f32x4){0.f, 0.f, 0.f, 0.f};

    for (int kt = 0; kt < 4; ++kt) {
        bf16x8 ah[4], al[4];
        #pragma unroll
        for (int mt = 0; mt < 4; ++mt) {
            ah[mt] = *(const bf16x8*)(xa + ((mt * 4 + kt) * 64 + lane) * 8);
            al[mt] = *(const bf16x8*)(xa + 8192 + ((mt * 4 + kt) * 64 + lane) * 8);
        }
        #pragma unroll
        for (int nl = 0; nl < 2; ++nl) {
            const int nt = 2 * wave + nl;
            const bf16x8 wh = *(const bf16x8*)(w1f + ((kt * 8 + nt) * 64 + lane) * 8);
            const bf16x8 wl = *(const bf16x8*)(w1f + 16384 + ((kt * 8 + nt) * 64 + lane) * 8);
            #pragma unroll
            for (int mt = 0; mt < 4; ++mt) {
                acc[mt][nl] = __builtin_amdgcn_mfma_f32_16x16x32_bf16(ah[mt], wh, acc[mt][nl], 0, 0, 0);
                acc[mt][nl] = __builtin_amdgcn_mfma_f32_16x16x32_bf16(al[mt], wh, acc[mt][nl], 0, 0, 0);
                acc[mt][nl] = __builtin_amdgcn_mfma_f32_16x16x32_bf16(ah[mt], wl, acc[mt][nl], 0, 0, 0);
            }
        }
    }
    __syncthreads();                               // xa dead; hs may overlay

    // ---- epilogue: bias + relu -> hs[node][130] ----
    {
        const int cA = 2 * wave * 16 + (lane & 15);
        const int cB = cA + 16;
        const float bvA = b1[cA], bvB = b1[cB];
        #pragma unroll
        for (int mt = 0; mt < 4; ++mt) {
            #pragma unroll
            for (int r = 0; r < 4; ++r) {
                const int node = mt * 16 + (lane >> 4) * 4 + r;
                hs[node * 130 + cA] = fmaxf(acc[mt][0][r] + bvA, 0.f);
                hs[node * 130 + cB] = fmaxf(acc[mt][1][r] + bvB, 0.f);
            }
        }
    }
    __syncthreads();

    // ---- phase 2: logits k in [8w, 8w+8) for node = lane ----
    {
        const int kw = 8 * wave;
        float lg[8];
        #pragma unroll
        for (int j = 0; j < 8; ++j) lg[j] = 0.f;
        const float* hrow = hs + lane * 130;
        #pragma unroll 4
        for (int c = 0; c < CC; c += 2) {
            const float2 hv = *(const float2*)(hrow + c);
            const float* Wr = W2 + c * KK + kw;            // uniform -> s_load
            #pragma unroll
            for (int j = 0; j < 8; ++j) lg[j] = fmaf(hv.x, Wr[j], lg[j]);
            #pragma unroll
            for (int j = 0; j < 8; ++j) lg[j] = fmaf(hv.y, Wr[KK + j], lg[j]);
        }
        #pragma unroll
        for (int j = 0; j < 8; ++j)
            lgT[(kw + j) * 66 + lane] = lg[j] + b2[kw + j]; // b2 uniform
    }
    __syncthreads();

    // ---- phase 3: wave 0 softmax per node, coalesced f4 store ----
    if (wave == 0) {
        float v[KK];
        float m = -3.4e38f;
        #pragma unroll
        for (int k = 0; k < KK; ++k) {
            v[k] = lgT[k * 66 + lane];
            m = fmaxf(m, v[k]);
        }
        float sum = 0.f;
        #pragma unroll
        for (int k = 0; k < KK; ++k) {
            v[k] = __expf(v[k] - m);
            sum += v[k];
        }
        const float inv = 1.f / sum;
        if (lane < nvalid) {
            float* gp = s_out + (size_t)(base + lane) * KK;
            #pragma unroll
            for (int k = 0; k < KK; k += 4)
                *(float4*)(gp + k) = make_float4(v[k] * inv, v[k+1] * inv,
                                                 v[k+2] * inv, v[k+3] * inv);
        }
    }
}

// ---------------------------------------------------------------------------
// Kernel 3: partial pooling, pure streaming — NO LDS, NO barriers.
// ---------------------------------------------------------------------------
__global__ __launch_bounds__(256) void hp_pool(
    const float* __restrict__ x,
    const float* __restrict__ s,
    const int* __restrict__ bounds,
    float* __restrict__ part,
    int nslices)
{
    const int b = blockIdx.x / nslices;
    const int p = blockIdx.x - b * nslices;
    const int t = threadIdx.x;

    const int gs  = bounds[b];
    const int cnt = bounds[b + 1] - gs;
    const int n0  = gs + (int)(((long long)cnt * p) / nslices);
    const int n1  = gs + (int)(((long long)cnt * (p + 1)) / nslices);

    const int k0 = (t >> 5) * 4;
    const int c0 = (t & 31) * 4;

    float a4[4][4] = {{0.f}};

    #pragma unroll 2
    for (int n = n0; n < n1; ++n) {
        const float4 xv = *(const float4*)(x + (size_t)n * CC + c0);
        const float4 sv = *(const float4*)(s + (size_t)n * KK + k0);
        a4[0][0] = fmaf(sv.x, xv.x, a4[0][0]); a4[0][1] = fmaf(sv.x, xv.y, a4[0][1]);
        a4[0][2] = fmaf(sv.x, xv.z, a4[0][2]); a4[0][3] = fmaf(sv.x, xv.w, a4[0][3]);
        a4[1][0] = fmaf(sv.y, xv.x, a4[1][0]); a4[1][1] = fmaf(sv.y, xv.y, a4[1][1]);
        a4[1][2] = fmaf(sv.y, xv.z, a4[1][2]); a4[1][3] = fmaf(sv.y, xv.w, a4[1][3]);
        a4[2][0] = fmaf(sv.z, xv.x, a4[2][0]); a4[2][1] = fmaf(sv.z, xv.y, a4[2][1]);
        a4[2][2] = fmaf(sv.z, xv.z, a4[2][2]); a4[2][3] = fmaf(sv.z, xv.w, a4[2][3]);
        a4[3][0] = fmaf(sv.w, xv.x, a4[3][0]); a4[3][1] = fmaf(sv.w, xv.y, a4[3][1]);
        a4[3][2] = fmaf(sv.w, xv.z, a4[3][2]); a4[3][3] = fmaf(sv.w, xv.w, a4[3][3]);
    }

    float* op = part + (size_t)blockIdx.x * KK * CC;
    #pragma unroll
    for (int a = 0; a < 4; ++a)
        *(float4*)&op[(k0 + a) * CC + c0] = make_float4(a4[a][0], a4[a][1], a4[a][2], a4[a][3]);
}

// ---------------------------------------------------------------------------
// Kernel 4: out[b] = sum of the nslices partial tiles.
// ---------------------------------------------------------------------------
__global__ __launch_bounds__(256) void hp_reduce(const float* __restrict__ part,
                                                 float* __restrict__ out,
                                                 int nslices) {
    const int i = (blockIdx.x * 256 + threadIdx.x) * 4;
    if (i < BB * KK * CC) {
        const int b = i >> 12;
        const int j = i & 4095;
        const float* pp = part + (size_t)b * nslices * 4096 + j;
        float4 r = make_float4(0.f, 0.f, 0.f, 0.f);
        for (int q = 0; q < nslices; ++q) {
            float4 v = *(const float4*)(pp + (size_t)q * 4096);
            r.x += v.x; r.y += v.y; r.z += v.z; r.w += v.w;
        }
        *(float4*)(out + i) = r;
    }
}

// ---------------------------------------------------------------------------
extern "C" void kernel_launch(void* const* d_in, const int* in_sizes, int n_in,
                              void* d_out, int out_size, void* d_ws, size_t ws_size,
                              hipStream_t stream) {
    const float* x     = (const float*)d_in[0];
    const int*   batch = (const int*)d_in[1];
    const float* W1    = (const float*)d_in[2];
    const float* b1    = (const float*)d_in[3];
    const float* W2    = (const float*)d_in[4];
    const float* b2    = (const float*)d_in[5];

    float* out = (float*)d_out;                    // [B,K,C] = 262144 floats
    float* s   = out + (size_t)BB * KK * CC;       // [N,K]   = 3200000 floats

    int*            bounds = (int*)d_ws;                       // 65 ints
    unsigned short* w1f    = (unsigned short*)((char*)d_ws + 1024);   // 64 KB
    float*          part   = (float*)((char*)d_ws + 1024 + 65536);

    int nslices = 16;
    while (nslices > 4 &&
           ws_size < 1024 + 65536 + (size_t)BB * nslices * KK * CC * 4)
        nslices >>= 1;

    hp_prep<<<8, 256, 0, stream>>>(batch, W1, bounds, w1f);
    hp_mlp<<<(NN + 63) / 64, 256, 0, stream>>>(x, w1f, b1, W2, b2, s);
    hp_pool<<<BB * nslices, 256, 0, stream>>>(x, s, bounds, part, nslices);
    hp_reduce<<<BB * KK * CC / (256 * 4), 256, 0, stream>>>(part, out, nslices);
}